// Round 1
// baseline (66.315 us; speedup 1.0000x reference)
//
#include <hip/hip_runtime.h>

#define BLOCK 256

// One thread per (b,n) atom. Tables in LDS; output staged in padded LDS then
// written coalesced as float4.
__global__ __launch_bounds__(BLOCK) void efp_kernel(
    const float* __restrict__ info,   // [M,7]
    const float* __restrict__ mask,   // [M]
    const float* __restrict__ W,      // [16,5]
    const float* __restrict__ bias,   // [16]
    const float* __restrict__ atom,   // [95,8]
    const float* __restrict__ typ,    // [6,4]
    float* __restrict__ out,          // [M,28]
    int ntiles)
{
    __shared__ float s_W[80];
    __shared__ float s_b[16];
    __shared__ float s_atom[95 * 8];
    __shared__ float s_typ[24];
    __shared__ float s_out[BLOCK * 29];   // 28 -> 29 pad: stride 29 coprime w/ 32 banks

    const int tid = threadIdx.x;

    // ---- stage tables once per block ----
    if (tid < 80) s_W[tid] = W[tid];
    if (tid < 16) s_b[tid] = bias[tid];
    for (int k = tid; k < 95 * 8; k += BLOCK) s_atom[k] = atom[k];
    if (tid < 24) s_typ[tid] = typ[tid];
    __syncthreads();

    for (int tile = blockIdx.x; tile < ntiles; tile += gridDim.x) {
        const long long base = (long long)tile * BLOCK;
        const long long i = base + tid;

        // ---- global loads (issue before barrier so latency overlaps) ----
        const float m = mask[i];
        const float* gi = info + i * 7;
        const float r0 = gi[0], r1 = gi[1], r2 = gi[2], r3 = gi[3], r4 = gi[4];
        const float r5 = gi[5], r6 = gi[6];

        // ---- per-atom compute (exact reference semantics) ----
        const float f0 = r0 * m, f1 = r1 * m, f2 = r2 * m, f3 = r3 * m, f4 = r4 * m;
        const int an = (int)(r5 * m);          // trunc toward zero, like .astype(int32)
        const int et = (int)(r6 * m);
        const bool active = (m >= 0.5f);
        const bool valid = active && (an >= 1) && (an <= 94);
        const int anc = min(max(an, 0), 94);
        const int etc = min(max(et, 0), 5);
        const float sc_ff  = active ? m : 0.0f;  // folds where(active,·,0) and final *mask
        const float sc_emb = valid ? m : 0.0f;

        __syncthreads();   // previous tile's coop-store reads of s_out are done

        float* so = s_out + tid * 29;
        #pragma unroll
        for (int o = 0; o < 16; ++o) {
            float acc = s_b[o];
            acc = fmaf(s_W[o * 5 + 0], f0, acc);
            acc = fmaf(s_W[o * 5 + 1], f1, acc);
            acc = fmaf(s_W[o * 5 + 2], f2, acc);
            acc = fmaf(s_W[o * 5 + 3], f3, acc);
            acc = fmaf(s_W[o * 5 + 4], f4, acc);
            so[o] = fmaxf(acc, 0.0f) * sc_ff;
        }
        #pragma unroll
        for (int k = 0; k < 8; ++k) so[16 + k] = s_atom[anc * 8 + k] * sc_emb;
        #pragma unroll
        for (int k = 0; k < 4; ++k) so[24 + k] = s_typ[etc * 4 + k] * sc_emb;

        __syncthreads();   // s_out fully written

        // ---- coalesced float4 store of the whole tile (BLOCK*28 floats) ----
        float4* go = reinterpret_cast<float4*>(out + base * 28);
        #pragma unroll
        for (int k = tid, it = 0; it < 7; ++it, k += BLOCK) {
            const int e = k * 4;          // float index within tile output
            const int row = e / 28;       // compiler lowers to magic-mul
            const int col = e - row * 28; // multiple of 4
            const float* sr = s_out + row * 29 + col;
            go[k] = make_float4(sr[0], sr[1], sr[2], sr[3]);
        }
    }
}

extern "C" void kernel_launch(void* const* d_in, const int* in_sizes, int n_in,
                              void* d_out, int out_size, void* d_ws, size_t ws_size,
                              hipStream_t stream) {
    const float* info = (const float*)d_in[0];   // [B,N,7]
    const float* mask = (const float*)d_in[1];   // [B,N]
    const float* W    = (const float*)d_in[2];   // [16,5]
    const float* bias = (const float*)d_in[3];   // [16]
    const float* atom = (const float*)d_in[4];   // [95,8]
    const float* typ  = (const float*)d_in[5];   // [6,4]
    float* out = (float*)d_out;

    const int M = in_sizes[1];                   // B*N = 2097152 (divisible by 256)
    const int ntiles = M / BLOCK;
    int grid = ntiles < 2048 ? ntiles : 2048;

    hipLaunchKernelGGL(efp_kernel, dim3(grid), dim3(BLOCK), 0, stream,
                       info, mask, W, bias, atom, typ, out, ntiles);
}